// Round 8
// baseline (390.160 us; speedup 1.0000x reference)
//
#include <hip/hip_runtime.h>

#define N0c 524288
#define N1c 131072
#define Bc  512
#define Dc  128
#define Hc  128
#define Cc  10
#define EPSc 1e-5f
#define PB_CH 4096

typedef unsigned short u16;
typedef __attribute__((ext_vector_type(8))) short bf16x8;
typedef __attribute__((ext_vector_type(4))) float f32x4;

__device__ __forceinline__ u16 f2bf(float f) {
    unsigned u = __builtin_bit_cast(unsigned, f);
    unsigned r = (u + 0x7fffu + ((u >> 16) & 1u)) >> 16;
    return (u16)r;
}
__device__ __forceinline__ float bf2f(u16 h) {
    return __builtin_bit_cast(float, (unsigned)h << 16);
}

// ---------------------------------------------------------------------------
// Histograms: blocks [0,512) parent1 (direct atomics, ~4-way);
// blocks [512,640) parent2 + tree1 (LDS hists).
// ---------------------------------------------------------------------------
__global__ __launch_bounds__(256) void k_count_all(
    const int* __restrict__ parent1, int* __restrict__ cnt1,
    const int* __restrict__ parent2, int* __restrict__ cnt2,
    const int* __restrict__ tree1, int* __restrict__ cntT1)
{
    __shared__ int hA[Bc], hB[Bc];
    const int b = blockIdx.x, tid = threadIdx.x;
    if (b < 512) {
        for (int i = b * 256 + tid; i < N0c; i += 512 * 256)
            atomicAdd(&cnt1[parent1[i]], 1);
    } else {
        for (int i = tid; i < Bc; i += 256) { hA[i] = 0; hB[i] = 0; }
        __syncthreads();
        for (int i = (b - 512) * 256 + tid; i < N1c; i += 128 * 256) {
            atomicAdd(&hA[parent2[i]], 1);
            atomicAdd(&hB[tree1[i]], 1);
        }
        __syncthreads();
        for (int i = tid; i < Bc; i += 256) {
            int v = hA[i]; if (v) atomicAdd(&cnt2[i], v);
            v = hB[i];     if (v) atomicAdd(&cntT1[i], v);
        }
    }
}

__global__ __launch_bounds__(256) void k_scan_local(const int* __restrict__ cnt,
                                                    int* __restrict__ off,
                                                    int* __restrict__ bsum, int n)
{
    __shared__ int s[256];
    int t = threadIdx.x;
    int i = blockIdx.x * 256 + t;
    int v = (i < n) ? cnt[i] : 0;
    s[t] = v; __syncthreads();
    for (int o = 1; o < 256; o <<= 1) {
        int x = (t >= o) ? s[t - o] : 0;
        __syncthreads();
        s[t] += x;
        __syncthreads();
    }
    if (i < n) off[i] = s[t] - v;
    if (t == 255) bsum[blockIdx.x] = s[255];
}

// blocks 0-511: add prefix(bsum) to off1 slice; 512: cnt2 scan; 513: cntT1.
__global__ __launch_bounds__(512) void k_scan_fin(
    const int* __restrict__ bsum, int* __restrict__ off1,
    const int* __restrict__ cnt2,  int* __restrict__ off2,
    const int* __restrict__ cntT1, int* __restrict__ offT1)
{
    __shared__ int s[512];
    const int t = threadIdx.x, b = blockIdx.x;
    if (b < 512) {
        s[t] = (t < b) ? bsum[t] : 0;
        __syncthreads();
        for (int o = 256; o; o >>= 1) {
            if (t < o) s[t] += s[t + o];
            __syncthreads();
        }
        int pre = s[0];
        if (t < 256) off1[b * 256 + t] += pre;
    } else {
        const int* src; int* dst;
        if (b == 512) { src = cnt2;  dst = off2;  }
        else          { src = cntT1; dst = offT1; }
        int v = src[t];
        s[t] = v; __syncthreads();
        for (int o = 1; o < 512; o <<= 1) {
            int x = (t >= o) ? s[t - o] : 0;
            __syncthreads();
            s[t] += x;
            __syncthreads();
        }
        dst[t] = s[t] - v;
    }
}

// ---------------------------------------------------------------------------
// Placement: [0,512) parent1 direct; [512,544) parent2 binned; [544,576) tree1.
// ---------------------------------------------------------------------------
__device__ __forceinline__ void place_binned(
    const int* __restrict__ idx, const int* __restrict__ off,
    int* __restrict__ cur, int* __restrict__ child, int n,
    int cb, int* h, int* base)
{
    const int tid = threadIdx.x;
    const int c0 = cb * PB_CH;
    const int c1 = min(c0 + PB_CH, n);
    for (int i = tid; i < Bc; i += 1024) h[i] = 0;
    __syncthreads();
    for (int i = c0 + tid; i < c1; i += 1024)
        atomicAdd(&h[idx[i]], 1);
    __syncthreads();
    for (int i = tid; i < Bc; i += 1024) {
        int v = h[i];
        base[i] = v ? atomicAdd(&cur[i], v) : 0;
    }
    __syncthreads();
    for (int i = tid; i < Bc; i += 1024) h[i] = 0;
    __syncthreads();
    for (int i = c0 + tid; i < c1; i += 1024) {
        int b = idx[i];
        int p = atomicAdd(&h[b], 1);
        child[off[b] + base[b] + p] = i;
    }
}

__global__ __launch_bounds__(1024) void k_place_all(
    const int* __restrict__ parent1, const int* __restrict__ off1,
    int* __restrict__ cur1, int* __restrict__ child1,
    const int* __restrict__ parent2, const int* __restrict__ off2,
    int* __restrict__ cur2, int* __restrict__ child2,
    const int* __restrict__ tree1, const int* __restrict__ offT1,
    int* __restrict__ curT1, int* __restrict__ childT1)
{
    __shared__ int h[Bc], base[Bc];
    const int b = blockIdx.x;
    if (b < 512) {
        int r = b * 1024 + threadIdx.x;   // 512*1024 == N0c
        int p = parent1[r];
        int pos = off1[p] + atomicAdd(&cur1[p], 1);
        child1[pos] = r;
    } else if (b < 544) {
        place_binned(parent2, off2, cur2, child2, N1c, b - 512, h, base);
    } else {
        place_binned(tree1, offT1, curT1, childT1, N1c, b - 544, h, base);
    }
}

// ---------------------------------------------------------------------------
// k_q: ONE streaming pass over h0. Per 16-row tile (split-bf16 A, MFMA):
//   Q[rows] = h0 @ W1          (bf16 out, natural row order, coalesced)
//   accl[tree0[row]][c] += h0 @ predW[0:128][c]   (LDS acc -> global atomics)
// 512 thr = 8 waves; each wave owns a 16-row tile per iteration.
// ---------------------------------------------------------------------------
__global__ __launch_bounds__(512) void k_q(
    const float* __restrict__ h0, const int* __restrict__ tree0,
    const float* __restrict__ W1, const float* __restrict__ predW,
    u16* __restrict__ Q, float* __restrict__ acc0)
{
    __shared__ __align__(16) u16 Wt[128 * 136];   // W1 bf16, [n][k], pad 136
    __shared__ __align__(16) u16 Pt[16 * 136];    // predW cols 0..9 (pad 16), [c][k]
    __shared__ float accl[Bc * Cc];               // 20 KB
    __shared__ __align__(16) u16 Cst[8][16 * 72]; // per-wave C staging, stride 72

    const int tid = threadIdx.x;
    for (int i = tid; i < 128 * 128; i += 512) {
        int k = i >> 7, n = i & 127;
        Wt[n * 136 + k] = f2bf(W1[i]);            // W1[k][n]
    }
    for (int i = tid; i < 16 * 128; i += 512) {
        int k = i >> 4, c = i & 15;
        Pt[c * 136 + k] = (c < Cc) ? f2bf(predW[k * Cc + c]) : (u16)0;
    }
    for (int i = tid; i < Bc * Cc; i += 512) accl[i] = 0.f;
    __syncthreads();

    const int wave = tid >> 6;
    const int l    = tid & 63;
    const int r16  = l & 15;
    const int kg   = l >> 4;          // 0..3

    for (int tile = blockIdx.x * 8 + wave; tile < N0c / 16; tile += 512 * 8) {
        const int row0 = tile * 16;
        const float* arow = h0 + (size_t)(row0 + r16) * 128 + kg * 8;

        bf16x8 ah[4], al[4];
        #pragma unroll
        for (int s = 0; s < 4; s++) {
            float4 f0 = *(const float4*)(arow + s * 32);
            float4 f1 = *(const float4*)(arow + s * 32 + 4);
            float f[8] = {f0.x, f0.y, f0.z, f0.w, f1.x, f1.y, f1.z, f1.w};
            #pragma unroll
            for (int j = 0; j < 8; j++) {
                u16 h = f2bf(f[j]);
                ah[s][j] = (short)h;
                al[s][j] = (short)f2bf(f[j] - bf2f(h));
            }
        }

        // ---- g0 projection (B = predW slice) ----
        f32x4 accP = (f32x4){0.f, 0.f, 0.f, 0.f};
        #pragma unroll
        for (int s = 0; s < 4; s++) {
            bf16x8 bp = *(const bf16x8*)(Pt + r16 * 136 + s * 32 + kg * 8);
            accP = __builtin_amdgcn_mfma_f32_16x16x32_bf16(ah[s], bp, accP, 0, 0, 0);
            accP = __builtin_amdgcn_mfma_f32_16x16x32_bf16(al[s], bp, accP, 0, 0, 0);
        }
        {
            int tr[4];
            #pragma unroll
            for (int j = 0; j < 4; j++) tr[j] = tree0[row0 + kg * 4 + j];
            if (r16 < Cc) {
                #pragma unroll
                for (int j = 0; j < 4; j++)
                    atomicAdd(&accl[tr[j] * Cc + r16], accP[j]);
            }
        }

        // ---- Q = h0 @ W1 (8 col-tiles), staged to LDS, flushed per half ----
        #pragma unroll
        for (int ct = 0; ct < 8; ct++) {
            f32x4 acc = (f32x4){0.f, 0.f, 0.f, 0.f};
            #pragma unroll
            for (int s = 0; s < 4; s++) {
                bf16x8 bw = *(const bf16x8*)(Wt + (ct * 16 + r16) * 136 + s * 32 + kg * 8);
                acc = __builtin_amdgcn_mfma_f32_16x16x32_bf16(ah[s], bw, acc, 0, 0, 0);
                acc = __builtin_amdgcn_mfma_f32_16x16x32_bf16(al[s], bw, acc, 0, 0, 0);
            }
            #pragma unroll
            for (int j = 0; j < 4; j++)
                Cst[wave][(kg * 4 + j) * 72 + (ct & 3) * 16 + r16] = f2bf(acc[j]);
            if ((ct & 3) == 3) {
                const int hh = ct >> 2;           // half 0 or 1
                const int row = r16, piece = kg;  // 16 rows x 4 x 32B
                const u16* sp = &Cst[wave][row * 72 + piece * 16];
                uint4 dlo_ = *(const uint4*)(sp);
                uint4 dhi_ = *(const uint4*)(sp + 8);
                u16* gp = Q + (size_t)(row0 + row) * 128 + hh * 64 + piece * 16;
                *(uint4*)(gp)     = dlo_;
                *(uint4*)(gp + 8) = dhi_;
            }
        }
    }

    __syncthreads();
    for (int i = tid; i < Bc * Cc; i += 512) {
        float v = accl[i];
        if (v != 0.f) atomicAdd(&acc0[i], v);
    }
}

// ---------------------------------------------------------------------------
// k_gather: parent-sorted segment-sum of Q rows (bf16, 256B/row) ->
// t1 = sum + b1, stored split-bf16 (phi/plo); BN-A column sum/sumsq.
// ---------------------------------------------------------------------------
__global__ __launch_bounds__(512) void k_gather(
    const u16* __restrict__ Q, const int* __restrict__ child1,
    const int* __restrict__ off1, const int* __restrict__ cnt1,
    const float* __restrict__ b1,
    u16* __restrict__ dhi, u16* __restrict__ dlo,
    float* __restrict__ ssum, float* __restrict__ ssq)
{
    __shared__ float lsum[128], lsq[128];
    const int tid = threadIdx.x;
    if (tid < 128) { lsum[tid] = 0.f; lsq[tid] = 0.f; }
    __syncthreads();

    const int lane = tid & 31;
    const int sub  = tid >> 5;
    float4 b4 = ((const float4*)b1)[lane];
    float s0=0,s1=0,s2=0,s3=0, q0=0,q1=0,q2=0,q3=0;

    for (int seg = blockIdx.x * 16 + sub; seg < N1c; seg += 1024 * 16) {
        const int beg = off1[seg], len = cnt1[seg];
        float ax=0, ay=0, az=0, aw=0;
        for (int c0 = 0; c0 < len; c0 += 8) {
            const int rem = len - c0;
            int idx = 0;
            if (lane < 8 && lane < rem) idx = child1[beg + c0 + lane];
            #pragma unroll
            for (int j = 0; j < 8; j++) {
                int r = __shfl(idx, j, 32);
                if (j < rem) {
                    ushort4 v = *(const ushort4*)(Q + (size_t)r * 128 + lane * 4);
                    ax += bf2f(v.x); ay += bf2f(v.y);
                    az += bf2f(v.z); aw += bf2f(v.w);
                }
            }
        }
        float tx = ax + b4.x, ty = ay + b4.y, tz = az + b4.z, tw = aw + b4.w;
        s0 += tx; s1 += ty; s2 += tz; s3 += tw;
        q0 += tx*tx; q1 += ty*ty; q2 += tz*tz; q3 += tw*tw;
        ushort4 hv, lv;
        hv.x = f2bf(tx); lv.x = f2bf(tx - bf2f(hv.x));
        hv.y = f2bf(ty); lv.y = f2bf(ty - bf2f(hv.y));
        hv.z = f2bf(tz); lv.z = f2bf(tz - bf2f(hv.z));
        hv.w = f2bf(tw); lv.w = f2bf(tw - bf2f(hv.w));
        *(ushort4*)(dhi + (size_t)seg * Hc + lane * 4) = hv;
        *(ushort4*)(dlo + (size_t)seg * Hc + lane * 4) = lv;
    }

    atomicAdd(&lsum[lane*4+0], s0); atomicAdd(&lsum[lane*4+1], s1);
    atomicAdd(&lsum[lane*4+2], s2); atomicAdd(&lsum[lane*4+3], s3);
    atomicAdd(&lsq [lane*4+0], q0); atomicAdd(&lsq [lane*4+1], q1);
    atomicAdd(&lsq [lane*4+2], q2); atomicAdd(&lsq [lane*4+3], q3);
    __syncthreads();
    if (tid < 128) {
        atomicAdd(&ssum[tid], lsum[tid]);
        atomicAdd(&ssq [tid], lsq [tid]);
    }
}

// ---------------------------------------------------------------------------
// Split-bf16 MFMA GEMM, 128 rows/block, in place: t4 = relu(bnA(t1))@W2+b2.
// ---------------------------------------------------------------------------
__global__ __launch_bounds__(512) void k_gemm_mfma(
    u16* __restrict__ Ahi, u16* __restrict__ Alo,
    const float* __restrict__ W, const float* __restrict__ bias,
    const float* __restrict__ bn_sum, const float* __restrict__ bn_sq,
    const float* __restrict__ bn_g, const float* __restrict__ bn_b, float invN,
    float* __restrict__ ssum, float* __restrict__ ssq)
{
    __shared__ __align__(16) u16 Wh[128 * 136];
    __shared__ __align__(16) u16 Wl[128 * 136];
    __shared__ float bl[128], scl[128], shl[128];
    __shared__ float lsum[128], lsq[128];

    const int tid = threadIdx.x;
    for (int i = tid; i < 128 * 128; i += 512) {
        int k = i >> 7, n = i & 127;
        float f = W[i];
        u16 h = f2bf(f);
        Wh[n * 136 + k] = h;
        Wl[n * 136 + k] = f2bf(f - bf2f(h));
    }
    if (tid < 128) {
        bl[tid] = bias[tid];
        lsum[tid] = 0.f; lsq[tid] = 0.f;
        float m = bn_sum[tid] * invN;
        float v = bn_sq[tid] * invN - m * m;
        float s = bn_g[tid] * rsqrtf(v + EPSc);
        scl[tid] = s;
        shl[tid] = bn_b[tid] - m * s;
    }
    __syncthreads();

    const int wave = tid >> 6;
    const int l    = tid & 63;
    const int r16  = l & 15;
    const int kg   = l >> 4;
    const int row0 = blockIdx.x * 128 + wave * 16;

    const u16* arow_h = Ahi + (size_t)(row0 + r16) * 128 + kg * 8;
    const u16* arow_l = Alo + (size_t)(row0 + r16) * 128 + kg * 8;

    f32x4 acc[8];
    #pragma unroll
    for (int nt = 0; nt < 8; nt++) acc[nt] = (f32x4){0.f, 0.f, 0.f, 0.f};

    #pragma unroll
    for (int kk = 0; kk < 4; kk++) {
        bf16x8 ah, al;
        bf16x8 rh = *(const bf16x8*)(arow_h + kk * 32);
        bf16x8 rl = *(const bf16x8*)(arow_l + kk * 32);
        const int kb = kk * 32 + kg * 8;
        #pragma unroll
        for (int j = 0; j < 8; j++) {
            float x = bf2f((u16)rh[j]) + bf2f((u16)rl[j]);
            float y = fmaxf(fmaf(x, scl[kb + j], shl[kb + j]), 0.f);
            u16 yh = f2bf(y);
            ah[j] = (short)yh;
            al[j] = (short)f2bf(y - bf2f(yh));
        }
        #pragma unroll
        for (int nt = 0; nt < 8; nt++) {
            const int bo = (nt * 16 + r16) * 136 + kk * 32 + kg * 8;
            bf16x8 bh = *(const bf16x8*)(Wh + bo);
            bf16x8 bw = *(const bf16x8*)(Wl + bo);
            acc[nt] = __builtin_amdgcn_mfma_f32_16x16x32_bf16(ah, bh, acc[nt], 0, 0, 0);
            acc[nt] = __builtin_amdgcn_mfma_f32_16x16x32_bf16(ah, bw, acc[nt], 0, 0, 0);
            acc[nt] = __builtin_amdgcn_mfma_f32_16x16x32_bf16(al, bh, acc[nt], 0, 0, 0);
        }
    }

    float v[8][4];
    #pragma unroll
    for (int nt = 0; nt < 8; nt++) {
        float b = bl[nt * 16 + r16];
        float s = 0.f, q = 0.f;
        #pragma unroll
        for (int j = 0; j < 4; j++) {
            float x = acc[nt][j] + b;
            v[nt][j] = x;
            s += x; q += x * x;
        }
        s += __shfl_xor(s, 16); s += __shfl_xor(s, 32);
        q += __shfl_xor(q, 16); q += __shfl_xor(q, 32);
        if (kg == 0) {
            atomicAdd(&lsum[nt * 16 + r16], s);
            atomicAdd(&lsq [nt * 16 + r16], q);
        }
    }
    __syncthreads();
    #pragma unroll
    for (int nt = 0; nt < 8; nt++) {
        #pragma unroll
        for (int j = 0; j < 4; j++) {
            int rl_ = wave * 16 + kg * 4 + j;
            int c   = nt * 16 + r16;
            float x = v[nt][j];
            u16 hh = f2bf(x);
            Wh[rl_ * 128 + c] = hh;
            Wl[rl_ * 128 + c] = f2bf(x - bf2f(hh));
        }
    }
    __syncthreads();
    {
        uint4* gh = (uint4*)(Ahi + (size_t)blockIdx.x * 128 * 128);
        uint4* gl = (uint4*)(Alo + (size_t)blockIdx.x * 128 * 128);
        const uint4* sh4 = (const uint4*)Wh;
        const uint4* sl4 = (const uint4*)Wl;
        for (int i = tid; i < 128 * 128 / 8; i += 512) {
            gh[i] = sh4[i];
            gl[i] = sl4[i];
        }
    }
    if (tid < 128) {
        atomicAdd(&ssum[tid], lsum[tid]);
        atomicAdd(&ssq [tid], lsq [tid]);
    }
}

// ---------------------------------------------------------------------------
// Fused level-2 pass over t4 (BN-B coeffs in prologue).
// ---------------------------------------------------------------------------
__global__ __launch_bounds__(512) void k_l2(
    const u16* __restrict__ shi, const u16* __restrict__ slo,
    const int* __restrict__ child2, const int* __restrict__ off2,
    const int* __restrict__ cnt2,
    const int* __restrict__ childT1, const int* __restrict__ offT1,
    const int* __restrict__ cntT1,
    const float* __restrict__ sumB, const float* __restrict__ sqB,
    const float* __restrict__ bng, const float* __restrict__ bnb,
    const float* __restrict__ predW,
    float* __restrict__ p2, float* __restrict__ acc1)
{
    __shared__ __align__(16) float scl[128], shl[128];
    const int tid = threadIdx.x;
    if (tid < 128) {
        float m = sumB[tid] * (1.f / N1c);
        float v = sqB[tid] * (1.f / N1c) - m * m;
        float s = bng[tid] * rsqrtf(v + EPSc);
        scl[tid] = s;
        shl[tid] = bnb[tid] - m * s;
    }
    __syncthreads();

    const int lane = tid & 31;
    const int sub  = tid >> 5;
    float4 sc4 = ((const float4*)scl)[lane];
    float4 sh4 = ((const float4*)shl)[lane];

    if (blockIdx.x < 512) {
        const int t = blockIdx.x * 16 + sub;
        const int seg = t % Bc;
        const int ch  = t / Bc;
        const int beg = off2[seg], len = cnt2[seg];
        int c0 = (int)(((long long)len * ch) / 16);
        int c1 = (int)(((long long)len * (ch + 1)) / 16);
        float4 acc = make_float4(0.f, 0.f, 0.f, 0.f);
        for (int c = c0; c < c1; ++c) {
            int r0 = child2[beg + c];
            ushort4 h = *(const ushort4*)(shi + (size_t)r0 * Hc + lane * 4);
            ushort4 lo = *(const ushort4*)(slo + (size_t)r0 * Hc + lane * 4);
            acc.x += fmaxf(fmaf(bf2f(h.x)+bf2f(lo.x), sc4.x, sh4.x), 0.f);
            acc.y += fmaxf(fmaf(bf2f(h.y)+bf2f(lo.y), sc4.y, sh4.y), 0.f);
            acc.z += fmaxf(fmaf(bf2f(h.z)+bf2f(lo.z), sc4.z, sh4.z), 0.f);
            acc.w += fmaxf(fmaf(bf2f(h.w)+bf2f(lo.w), sc4.w, sh4.w), 0.f);
        }
        float* d = p2 + (size_t)seg * Hc + lane * 4;
        atomicAdd(d + 0, acc.x);
        atomicAdd(d + 1, acc.y);
        atomicAdd(d + 2, acc.z);
        atomicAdd(d + 3, acc.w);
    } else {
        float4 wreg[Cc];
        #pragma unroll
        for (int cc = 0; cc < Cc; cc++) {
            wreg[cc].x = predW[(Hc + lane*4 + 0) * Cc + cc];
            wreg[cc].y = predW[(Hc + lane*4 + 1) * Cc + cc];
            wreg[cc].z = predW[(Hc + lane*4 + 2) * Cc + cc];
            wreg[cc].w = predW[(Hc + lane*4 + 3) * Cc + cc];
        }
        const int t = (blockIdx.x - 512) * 16 + sub;
        const int tr = t & (Bc - 1);
        const int ch = t >> 9;
        const int beg = offT1[tr], len = cntT1[tr];
        int c0 = (int)(((long long)len * ch) / 16);
        int c1 = (int)(((long long)len * (ch + 1)) / 16);
        float4 acc = make_float4(0.f, 0.f, 0.f, 0.f);
        for (int c = c0; c < c1; ++c) {
            int r0 = childT1[beg + c];
            ushort4 h = *(const ushort4*)(shi + (size_t)r0 * Hc + lane * 4);
            ushort4 lo = *(const ushort4*)(slo + (size_t)r0 * Hc + lane * 4);
            acc.x += fmaxf(fmaf(bf2f(h.x)+bf2f(lo.x), sc4.x, sh4.x), 0.f);
            acc.y += fmaxf(fmaf(bf2f(h.y)+bf2f(lo.y), sc4.y, sh4.y), 0.f);
            acc.z += fmaxf(fmaf(bf2f(h.z)+bf2f(lo.z), sc4.z, sh4.z), 0.f);
            acc.w += fmaxf(fmaf(bf2f(h.w)+bf2f(lo.w), sc4.w, sh4.w), 0.f);
        }
        float pv[Cc];
        #pragma unroll
        for (int cc = 0; cc < Cc; cc++) {
            pv[cc] = acc.x * wreg[cc].x + acc.y * wreg[cc].y
                   + acc.z * wreg[cc].z + acc.w * wreg[cc].w;
        }
        #pragma unroll
        for (int o = 16; o; o >>= 1) {
            #pragma unroll
            for (int cc = 0; cc < Cc; cc++) pv[cc] += __shfl_xor(pv[cc], o, 32);
        }
        if (lane == 0) {
            #pragma unroll
            for (int cc = 0; cc < Cc; cc++) atomicAdd(&acc1[tr * Cc + cc], pv[cc]);
        }
    }
}

// ---------------------------------------------------------------------------
// fp32 GEMM for the tiny level-2 MLP (BN folded when BN_IN=1).
// ---------------------------------------------------------------------------
template<int BN_IN>
__global__ __launch_bounds__(256) void k_gemm2(
    const float* __restrict__ in, float* __restrict__ out,
    const float* __restrict__ W, const float* __restrict__ bias,
    const float* __restrict__ bn_sum, const float* __restrict__ bn_sq,
    const float* __restrict__ bn_g, const float* __restrict__ bn_b,
    float* __restrict__ ssum, float* __restrict__ ssq)
{
    __shared__ float Wlds[Hc * Hc];
    __shared__ float inl[32 * Hc];
    __shared__ __align__(16) float scl[128], shl[128];

    const int tid = threadIdx.x;
    if (BN_IN && tid < 128) {
        float m = bn_sum[tid] * (1.f / Bc);
        float v = bn_sq[tid] * (1.f / Bc) - m * m;
        float s = bn_g[tid] * rsqrtf(v + EPSc);
        scl[tid] = s;
        shl[tid] = bn_b[tid] - m * s;
    }
    {
        const float4* W4 = (const float4*)W;
        float4* Wl4 = (float4*)Wlds;
        for (int i = tid; i < Hc * Hc / 4; i += 256) Wl4[i] = W4[i];
    }
    __syncthreads();
    const int row0 = blockIdx.x * 32;
    for (int i = tid; i < 32 * 32; i += 256) {
        int r = i >> 5, g = i & 31;
        float4 v = ((const float4*)(in + (size_t)(row0 + r) * Hc))[g];
        if (BN_IN) {
            float4 sc = ((const float4*)scl)[g];
            float4 sh = ((const float4*)shl)[g];
            v.x = fmaxf(v.x * sc.x + sh.x, 0.f);
            v.y = fmaxf(v.y * sc.y + sh.y, 0.f);
            v.z = fmaxf(v.z * sc.z + sh.z, 0.f);
            v.w = fmaxf(v.w * sc.w + sh.w, 0.f);
        }
        ((float4*)(inl + r * Hc))[g] = v;
    }
    __syncthreads();

    const int rg = tid >> 5;
    const int cg = tid & 31;
    float acc[4][4] = {{0.f}};
    for (int k = 0; k < Hc; k += 4) {
        float a[4][4], w[4][4];
        #pragma unroll
        for (int r = 0; r < 4; r++) {
            float4 t = *(const float4*)&inl[(rg*4 + r) * Hc + k];
            a[r][0] = t.x; a[r][1] = t.y; a[r][2] = t.z; a[r][3] = t.w;
        }
        #pragma unroll
        for (int kk = 0; kk < 4; kk++) {
            float4 t = *(const float4*)&Wlds[(k + kk) * Hc + cg*4];
            w[kk][0] = t.x; w[kk][1] = t.y; w[kk][2] = t.z; w[kk][3] = t.w;
        }
        #pragma unroll
        for (int r = 0; r < 4; r++)
            #pragma unroll
            for (int kk = 0; kk < 4; kk++)
                #pragma unroll
                for (int c = 0; c < 4; c++)
                    acc[r][c] = fmaf(a[r][kk], w[kk][c], acc[r][c]);
    }

    float b4[4];
    #pragma unroll
    for (int c = 0; c < 4; c++) b4[c] = bias[cg*4 + c];
    float s[4] = {0.f,0.f,0.f,0.f}, q[4] = {0.f,0.f,0.f,0.f};
    #pragma unroll
    for (int r = 0; r < 4; r++) {
        float v0 = acc[r][0] + b4[0];
        float v1 = acc[r][1] + b4[1];
        float v2 = acc[r][2] + b4[2];
        float v3 = acc[r][3] + b4[3];
        float4 o; o.x = v0; o.y = v1; o.z = v2; o.w = v3;
        s[0] += v0; s[1] += v1; s[2] += v2; s[3] += v3;
        q[0] += v0*v0; q[1] += v1*v1; q[2] += v2*v2; q[3] += v3*v3;
        *(float4*)&out[(size_t)(row0 + rg*4 + r) * Hc + cg*4] = o;
    }

    __syncthreads();
    #pragma unroll
    for (int c = 0; c < 4; c++) inl[rg * Hc + cg*4 + c] = s[c];
    __syncthreads();
    if (tid < Hc) {
        float t = 0.f;
        #pragma unroll
        for (int g = 0; g < 8; g++) t += inl[g * Hc + tid];
        atomicAdd(&ssum[tid], t);
    }
    __syncthreads();
    #pragma unroll
    for (int c = 0; c < 4; c++) inl[rg * Hc + cg*4 + c] = q[c];
    __syncthreads();
    if (tid < Hc) {
        float t = 0.f;
        #pragma unroll
        for (int g = 0; g < 8; g++) t += inl[g * Hc + tid];
        atomicAdd(&ssq[tid], t);
    }
}

// ---------------------------------------------------------------------------
// Final: BN-D from stats; logits + softmax.
// ---------------------------------------------------------------------------
__global__ __launch_bounds__(128) void k_final(
    const float* __restrict__ u2,
    const float* __restrict__ sumD, const float* __restrict__ sqD,
    const float* __restrict__ bng, const float* __restrict__ bnb,
    const float* __restrict__ acc0, const float* __restrict__ acc1,
    const float* __restrict__ predW, const float* __restrict__ predb,
    float* __restrict__ out)
{
    __shared__ float h[Hc];
    __shared__ float wl[Hc * Cc];
    __shared__ float lg[Cc], ex[Cc];
    int b = blockIdx.x, t = threadIdx.x;
    for (int i = t; i < Hc * Cc; i += 128) wl[i] = predW[(2*Hc) * Cc + i];
    {
        float m = sumD[t] * (1.f / Bc);
        float v = sqD[t] * (1.f / Bc) - m * m;
        float s = bng[t] * rsqrtf(v + EPSc);
        float x = u2[(size_t)b * Hc + t];
        h[t] = fmaxf(x * s + (bnb[t] - m * s), 0.f);
    }
    __syncthreads();
    if (t < Cc) {
        float s = predb[t] + acc0[b * Cc + t] + acc1[b * Cc + t];
        for (int d = 0; d < Hc; d++) s += h[d] * wl[d * Cc + t];
        lg[t] = s;
    }
    __syncthreads();
    if (t < Cc) {
        float m = lg[0];
        #pragma unroll
        for (int c = 1; c < Cc; c++) m = fmaxf(m, lg[c]);
        ex[t] = expf(lg[t] - m);
    }
    __syncthreads();
    if (t < Cc) {
        float s = 0.f;
        #pragma unroll
        for (int c = 0; c < Cc; c++) s += ex[c];
        out[b * Cc + t] = ex[t] / s;
    }
}

extern "C" void kernel_launch(void* const* d_in, const int* in_sizes, int n_in,
                              void* d_out, int out_size, void* d_ws, size_t ws_size,
                              hipStream_t stream) {
    const float* h0      = (const float*)d_in[0];
    const int*   parent1 = (const int*)d_in[1];
    const int*   parent2 = (const int*)d_in[2];
    const int*   tree0   = (const int*)d_in[3];
    const int*   tree1   = (const int*)d_in[4];
    const float* m1W1 = (const float*)d_in[5];
    const float* m1b1 = (const float*)d_in[6];
    const float* m1bng = (const float*)d_in[7];
    const float* m1bnb = (const float*)d_in[8];
    const float* m1W2 = (const float*)d_in[9];
    const float* m1b2 = (const float*)d_in[10];
    const float* bn1g = (const float*)d_in[11];
    const float* bn1b = (const float*)d_in[12];
    const float* m2W1 = (const float*)d_in[13];
    const float* m2b1 = (const float*)d_in[14];
    const float* m2bng = (const float*)d_in[15];
    const float* m2bnb = (const float*)d_in[16];
    const float* m2W2 = (const float*)d_in[17];
    const float* m2b2 = (const float*)d_in[18];
    const float* bn2g = (const float*)d_in[19];
    const float* bn2b = (const float*)d_in[20];
    const float* predW = (const float*)d_in[21];
    const float* predb = (const float*)d_in[22];
    float* out = (float*)d_out;

    // ---- workspace layout ----
    u16* Q   = (u16*)d_ws;                              // N0*128 bf16 (128 MB)
    u16* phi = Q + (size_t)N0c * Hc;                    // N1*128 (t1/t4 hi)
    u16* plo = phi + (size_t)N1c * Hc;                  // N1*128 (lo)
    float* zbase = (float*)(plo + (size_t)N1c * Hc);
    float* p2    = zbase;                               // 512*128
    float* acc0  = p2 + Bc * Hc;                        // 5120
    float* acc1  = acc0 + Bc * Cc;                      // 5120
    float* stats = acc1 + Bc * Cc;                      // 8*128
    int* cnt1   = (int*)(stats + 8 * Hc);               // 131072
    int* cur1   = cnt1 + N1c;                           // 131072
    int* cnt2   = cur1 + N1c;                           // 512
    int* cur2   = cnt2 + Bc;
    int* cntT1  = cur2 + Bc;
    int* curT1  = cntT1 + Bc;
    // --- end of zero region ---
    int* zend   = curT1 + Bc;
    int* off1   = zend;                  // 131072
    int* bsum   = off1 + N1c;            // 512
    int* off2   = bsum + Bc;             // 512
    int* offT1  = off2 + Bc;             // 512
    int* child1 = offT1 + Bc;            // 524288
    int* child2 = child1 + N0c;          // 131072
    int* childT1= child2 + N1c;          // 131072
    float* u1   = (float*)(childT1 + N1c);              // 512*128
    float* u2   = u1 + Bc * Hc;                         // 512*128

    float* sumA = stats + 0 * Hc; float* sqA = stats + 1 * Hc;
    float* sumB = stats + 2 * Hc; float* sqB = stats + 3 * Hc;
    float* sumC = stats + 4 * Hc; float* sqC = stats + 5 * Hc;
    float* sumD = stats + 6 * Hc; float* sqD = stats + 7 * Hc;

    const size_t zero_bytes = (char*)zend - (char*)zbase;
    hipMemsetAsync(zbase, 0, zero_bytes, stream);

    // ---- counting sorts ----
    k_count_all<<<640, 256, 0, stream>>>(parent1, cnt1, parent2, cnt2, tree1, cntT1);
    k_scan_local<<<N1c / 256, 256, 0, stream>>>(cnt1, off1, bsum, N1c);
    k_scan_fin<<<514, 512, 0, stream>>>(bsum, off1, cnt2, off2, cntT1, offT1);
    k_place_all<<<576, 1024, 0, stream>>>(parent1, off1, cur1, child1,
                                          parent2, off2, cur2, child2,
                                          tree1, offT1, curT1, childT1);

    // ---- level 1: streaming GEMM+proj, then gather on bf16 Q ----
    k_q<<<512, 512, 0, stream>>>(h0, tree0, m1W1, predW, Q, acc0);
    k_gather<<<1024, 512, 0, stream>>>(Q, child1, off1, cnt1, m1b1,
                                       phi, plo, sumA, sqA);

    // ---- layer-1 second GEMM (BN-A folded), in place ----
    k_gemm_mfma<<<N1c / 128, 512, 0, stream>>>(phi, plo, m1W2, m1b2,
                                               sumA, sqA, m1bng, m1bnb,
                                               1.f / N1c, sumB, sqB);

    // ---- level 2: fused gather + g1 projection ----
    k_l2<<<1024, 512, 0, stream>>>(phi, plo, child2, off2, cnt2,
                                   childT1, offT1, cntT1,
                                   sumB, sqB, bn1g, bn1b, predW, p2, acc1);

    // ---- layer-2 MLP (BN folded) + final ----
    k_gemm2<0><<<Bc / 32, 256, 0, stream>>>(p2, u1, m2W1, m2b1,
                                            nullptr, nullptr, nullptr, nullptr,
                                            sumC, sqC);
    k_gemm2<1><<<Bc / 32, 256, 0, stream>>>(u1, u2, m2W2, m2b2,
                                            sumC, sqC, m2bng, m2bnb,
                                            sumD, sqD);
    k_final<<<Bc, 128, 0, stream>>>(u2, sumD, sqD, bn2g, bn2b,
                                    acc0, acc1, predW, predb, out);
}

// Round 9
// 378.807 us; speedup vs baseline: 1.0300x; 1.0300x over previous
//
#include <hip/hip_runtime.h>

#define N0c 524288
#define N1c 131072
#define Bc  512
#define Dc  128
#define Hc  128
#define Cc  10
#define EPSc 1e-5f
#define PB_CH 4096

typedef unsigned short u16;
typedef unsigned int u32;
typedef __attribute__((ext_vector_type(8))) short bf16x8;
typedef __attribute__((ext_vector_type(4))) float f32x4;

__device__ __forceinline__ u16 f2bf(float f) {
    unsigned u = __builtin_bit_cast(unsigned, f);
    unsigned r = (u + 0x7fffu + ((u >> 16) & 1u)) >> 16;
    return (u16)r;
}
__device__ __forceinline__ float bf2f(u16 h) {
    return __builtin_bit_cast(float, (unsigned)h << 16);
}
__device__ __forceinline__ u32 packsplit(float x) {
    u16 h = f2bf(x);
    u16 l = f2bf(x - bf2f(h));
    return (u32)h | ((u32)l << 16);
}

// ---------------------------------------------------------------------------
// Histograms: blocks [0,512) parent1 (direct atomics, ~4-way);
// blocks [512,640) parent2 + tree1 (LDS hists).
// ---------------------------------------------------------------------------
__global__ __launch_bounds__(256) void k_count_all(
    const int* __restrict__ parent1, int* __restrict__ cnt1,
    const int* __restrict__ parent2, int* __restrict__ cnt2,
    const int* __restrict__ tree1, int* __restrict__ cntT1)
{
    __shared__ int hA[Bc], hB[Bc];
    const int b = blockIdx.x, tid = threadIdx.x;
    if (b < 512) {
        for (int i = b * 256 + tid; i < N0c; i += 512 * 256)
            atomicAdd(&cnt1[parent1[i]], 1);
    } else {
        for (int i = tid; i < Bc; i += 256) { hA[i] = 0; hB[i] = 0; }
        __syncthreads();
        for (int i = (b - 512) * 256 + tid; i < N1c; i += 128 * 256) {
            atomicAdd(&hA[parent2[i]], 1);
            atomicAdd(&hB[tree1[i]], 1);
        }
        __syncthreads();
        for (int i = tid; i < Bc; i += 256) {
            int v = hA[i]; if (v) atomicAdd(&cnt2[i], v);
            v = hB[i];     if (v) atomicAdd(&cntT1[i], v);
        }
    }
}

__global__ __launch_bounds__(256) void k_scan_local(const int* __restrict__ cnt,
                                                    int* __restrict__ off,
                                                    int* __restrict__ bsum, int n)
{
    __shared__ int s[256];
    int t = threadIdx.x;
    int i = blockIdx.x * 256 + t;
    int v = (i < n) ? cnt[i] : 0;
    s[t] = v; __syncthreads();
    for (int o = 1; o < 256; o <<= 1) {
        int x = (t >= o) ? s[t - o] : 0;
        __syncthreads();
        s[t] += x;
        __syncthreads();
    }
    if (i < n) off[i] = s[t] - v;
    if (t == 255) bsum[blockIdx.x] = s[255];
}

// blocks 0-511: add prefix(bsum) to off1 slice; 512: cnt2 scan; 513: cntT1.
__global__ __launch_bounds__(512) void k_scan_fin(
    const int* __restrict__ bsum, int* __restrict__ off1,
    const int* __restrict__ cnt2,  int* __restrict__ off2,
    const int* __restrict__ cntT1, int* __restrict__ offT1)
{
    __shared__ int s[512];
    const int t = threadIdx.x, b = blockIdx.x;
    if (b < 512) {
        s[t] = (t < b) ? bsum[t] : 0;
        __syncthreads();
        for (int o = 256; o; o >>= 1) {
            if (t < o) s[t] += s[t + o];
            __syncthreads();
        }
        int pre = s[0];
        if (t < 256) off1[b * 256 + t] += pre;
    } else {
        const int* src; int* dst;
        if (b == 512) { src = cnt2;  dst = off2;  }
        else          { src = cntT1; dst = offT1; }
        int v = src[t];
        s[t] = v; __syncthreads();
        for (int o = 1; o < 512; o <<= 1) {
            int x = (t >= o) ? s[t - o] : 0;
            __syncthreads();
            s[t] += x;
            __syncthreads();
        }
        dst[t] = s[t] - v;
    }
}

// 512-thread binned place (for the two 512-bin sorts), as a device fn.
__device__ __forceinline__ void place_binned(
    const int* __restrict__ idx, const int* __restrict__ off,
    int* __restrict__ cur, int* __restrict__ child, int n,
    int cb, int* h, int* base)
{
    const int tid = threadIdx.x;
    const int c0 = cb * PB_CH;
    const int c1 = min(c0 + PB_CH, n);
    for (int i = tid; i < Bc; i += 512) h[i] = 0;
    __syncthreads();
    for (int i = c0 + tid; i < c1; i += 512)
        atomicAdd(&h[idx[i]], 1);
    __syncthreads();
    for (int i = tid; i < Bc; i += 512) {
        int v = h[i];
        base[i] = v ? atomicAdd(&cur[i], v) : 0;
    }
    __syncthreads();
    for (int i = tid; i < Bc; i += 512) h[i] = 0;
    __syncthreads();
    for (int i = c0 + tid; i < c1; i += 512) {
        int b = idx[i];
        int p = atomicAdd(&h[b], 1);
        child[off[b] + base[b] + p] = i;
    }
}

// ---------------------------------------------------------------------------
// k_s: streaming pass over h0 (blocks [0,1024)):
//   - g0 projection via MFMA (tree0 in natural order, LDS accumulate)
//   - convert rows to bf16 and SCATTER into parent1-sorted slots of h0s
//     (randomness moved to fire-and-forget writes; gather becomes sequential)
// Blocks [1024,1088): binned place for parent2 / tree1 (independent work).
// ---------------------------------------------------------------------------
__global__ __launch_bounds__(512) void k_s(
    const float* __restrict__ h0, const int* __restrict__ tree0,
    const int* __restrict__ parent1, const int* __restrict__ off1,
    int* __restrict__ cur1, const float* __restrict__ predW,
    u16* __restrict__ h0s, float* __restrict__ acc0,
    const int* __restrict__ parent2, const int* __restrict__ off2,
    int* __restrict__ cur2, int* __restrict__ child2,
    const int* __restrict__ tree1, const int* __restrict__ offT1,
    int* __restrict__ curT1, int* __restrict__ childT1)
{
    __shared__ __align__(16) u16 Pt[16 * 136];   // predW cols 0..9, [c][k]
    __shared__ float accl[Bc * Cc];              // 20 KB
    __shared__ int hh[Bc], hbase[Bc];

    const int tid = threadIdx.x;
    if (blockIdx.x >= 1024) {
        if (blockIdx.x < 1056)
            place_binned(parent2, off2, cur2, child2, N1c, blockIdx.x - 1024, hh, hbase);
        else
            place_binned(tree1, offT1, curT1, childT1, N1c, blockIdx.x - 1056, hh, hbase);
        return;
    }

    for (int i = tid; i < 16 * 128; i += 512) {
        int k = i >> 4, c = i & 15;
        Pt[c * 136 + k] = (c < Cc) ? f2bf(predW[k * Cc + c]) : (u16)0;
    }
    for (int i = tid; i < Bc * Cc; i += 512) accl[i] = 0.f;
    __syncthreads();

    const int wave = tid >> 6;
    const int l    = tid & 63;
    const int r16  = l & 15;
    const int kg   = l >> 4;

    for (int tile = blockIdx.x * 8 + wave; tile < N0c / 16; tile += 1024 * 8) {
        const int row0 = tile * 16;
        const float* arow = h0 + (size_t)(row0 + r16) * 128 + kg * 8;

        bf16x8 ah[4], al[4];
        #pragma unroll
        for (int s = 0; s < 4; s++) {
            float4 f0 = *(const float4*)(arow + s * 32);
            float4 f1 = *(const float4*)(arow + s * 32 + 4);
            float f[8] = {f0.x, f0.y, f0.z, f0.w, f1.x, f1.y, f1.z, f1.w};
            #pragma unroll
            for (int j = 0; j < 8; j++) {
                u16 h = f2bf(f[j]);
                ah[s][j] = (short)h;
                al[s][j] = (short)f2bf(f[j] - bf2f(h));
            }
        }

        // ---- scatter bf16 row to its sorted slot ----
        int pos = 0;
        if (l < 16) {
            int p = parent1[row0 + l];
            pos = off1[p] + atomicAdd(&cur1[p], 1);
        }
        int posb = __shfl(pos, r16, 64);
        u16* dst = h0s + (size_t)posb * 128 + kg * 8;
        #pragma unroll
        for (int s = 0; s < 4; s++)
            *(bf16x8*)(dst + s * 32) = ah[s];

        // ---- g0 projection (2-term, B = bf16 predW slice) ----
        f32x4 accP = (f32x4){0.f, 0.f, 0.f, 0.f};
        #pragma unroll
        for (int s = 0; s < 4; s++) {
            bf16x8 bp = *(const bf16x8*)(Pt + r16 * 136 + s * 32 + kg * 8);
            accP = __builtin_amdgcn_mfma_f32_16x16x32_bf16(ah[s], bp, accP, 0, 0, 0);
            accP = __builtin_amdgcn_mfma_f32_16x16x32_bf16(al[s], bp, accP, 0, 0, 0);
        }
        int tr[4];
        #pragma unroll
        for (int j = 0; j < 4; j++) tr[j] = tree0[row0 + kg * 4 + j];
        if (r16 < Cc) {
            #pragma unroll
            for (int j = 0; j < 4; j++)
                atomicAdd(&accl[tr[j] * Cc + r16], accP[j]);
        }
    }

    __syncthreads();
    for (int i = tid; i < Bc * Cc; i += 512) {
        float v = accl[i];
        if (v != 0.f) atomicAdd(&acc0[i], v);
    }
}

// ---------------------------------------------------------------------------
// k_gather_c: segments are CONTIGUOUS runs in h0s -> pure sequential sweep.
// p1 = sum of rows (fp32 accum), stored packed split-bf16 (u32 = hi | lo<<16).
// ---------------------------------------------------------------------------
__global__ __launch_bounds__(512) void k_gather_c(
    const u16* __restrict__ h0s, const int* __restrict__ off1,
    const int* __restrict__ cnt1, u32* __restrict__ pp)
{
    const int lane = threadIdx.x & 31;
    const int sub  = threadIdx.x >> 5;
    for (int seg = blockIdx.x * 16 + sub; seg < N1c; seg += 2048 * 16) {
        const int beg = off1[seg], len = cnt1[seg];
        float4 acc = make_float4(0.f, 0.f, 0.f, 0.f);
        const u16* base = h0s + (size_t)beg * 128 + lane * 4;
        for (int j = 0; j < len; j++) {
            ushort4 v = *(const ushort4*)(base + (size_t)j * 128);
            acc.x += bf2f(v.x); acc.y += bf2f(v.y);
            acc.z += bf2f(v.z); acc.w += bf2f(v.w);
        }
        uint4 o;
        o.x = packsplit(acc.x); o.y = packsplit(acc.y);
        o.z = packsplit(acc.z); o.w = packsplit(acc.w);
        *(uint4*)(pp + (size_t)seg * 128 + lane * 4) = o;
    }
}

// ---------------------------------------------------------------------------
// Split-bf16 MFMA GEMM on PACKED rows, 128 rows/block, in place:
//   out = f(in) @ W + bias, f = identity (BN_IN=0) or relu(bn(x)) (BN_IN=1,
//   coeffs computed from batch stats in prologue). Emits column sum/sumsq.
// ---------------------------------------------------------------------------
template<int BN_IN>
__global__ __launch_bounds__(512) void k_gemm_mfma(
    u32* __restrict__ App,
    const float* __restrict__ W, const float* __restrict__ bias,
    const float* __restrict__ bn_sum, const float* __restrict__ bn_sq,
    const float* __restrict__ bn_g, const float* __restrict__ bn_b, float invN,
    float* __restrict__ ssum, float* __restrict__ ssq)
{
    __shared__ __align__(16) u16 WB[2 * 128 * 136];   // Wh | Wl; reused as u32 staging
    u16* Wh = WB;
    u16* Wl = WB + 128 * 136;
    __shared__ float bl[128], scl[128], shl[128];
    __shared__ float lsum[128], lsq[128];

    const int tid = threadIdx.x;
    for (int i = tid; i < 128 * 128; i += 512) {
        int k = i >> 7, n = i & 127;
        float f = W[i];
        u16 h = f2bf(f);
        Wh[n * 136 + k] = h;
        Wl[n * 136 + k] = f2bf(f - bf2f(h));
    }
    if (tid < 128) {
        bl[tid] = bias[tid];
        lsum[tid] = 0.f; lsq[tid] = 0.f;
        if (BN_IN) {
            float m = bn_sum[tid] * invN;
            float v = bn_sq[tid] * invN - m * m;
            float s = bn_g[tid] * rsqrtf(v + EPSc);
            scl[tid] = s;
            shl[tid] = bn_b[tid] - m * s;
        }
    }
    __syncthreads();

    const int wave = tid >> 6;
    const int l    = tid & 63;
    const int r16  = l & 15;
    const int kg   = l >> 4;
    const int row0 = blockIdx.x * 128 + wave * 16;

    const u32* arow = App + (size_t)(row0 + r16) * 128 + kg * 8;

    f32x4 acc[8];
    #pragma unroll
    for (int nt = 0; nt < 8; nt++) acc[nt] = (f32x4){0.f, 0.f, 0.f, 0.f};

    #pragma unroll
    for (int kk = 0; kk < 4; kk++) {
        uint4 pa = *(const uint4*)(arow + kk * 32);
        uint4 pb = *(const uint4*)(arow + kk * 32 + 4);
        u32 p[8] = {pa.x, pa.y, pa.z, pa.w, pb.x, pb.y, pb.z, pb.w};
        bf16x8 ah, al;
        if (BN_IN == 0) {
            #pragma unroll
            for (int j = 0; j < 8; j++) {
                ah[j] = (short)(u16)p[j];
                al[j] = (short)(u16)(p[j] >> 16);
            }
        } else {
            const int kb = kk * 32 + kg * 8;
            #pragma unroll
            for (int j = 0; j < 8; j++) {
                float x = bf2f((u16)p[j]) + bf2f((u16)(p[j] >> 16));
                float y = fmaxf(fmaf(x, scl[kb + j], shl[kb + j]), 0.f);
                u16 yh = f2bf(y);
                ah[j] = (short)yh;
                al[j] = (short)f2bf(y - bf2f(yh));
            }
        }
        #pragma unroll
        for (int nt = 0; nt < 8; nt++) {
            const int bo = (nt * 16 + r16) * 136 + kk * 32 + kg * 8;
            bf16x8 bh = *(const bf16x8*)(Wh + bo);
            bf16x8 bw = *(const bf16x8*)(Wl + bo);
            acc[nt] = __builtin_amdgcn_mfma_f32_16x16x32_bf16(ah, bh, acc[nt], 0, 0, 0);
            acc[nt] = __builtin_amdgcn_mfma_f32_16x16x32_bf16(ah, bw, acc[nt], 0, 0, 0);
            acc[nt] = __builtin_amdgcn_mfma_f32_16x16x32_bf16(al, bh, acc[nt], 0, 0, 0);
        }
    }

    // epilogue: bias + stats (C/D layout: col = l&15, row = (l>>4)*4 + j)
    float v[8][4];
    #pragma unroll
    for (int nt = 0; nt < 8; nt++) {
        float b = bl[nt * 16 + r16];
        float s = 0.f, q = 0.f;
        #pragma unroll
        for (int j = 0; j < 4; j++) {
            float x = acc[nt][j] + b;
            v[nt][j] = x;
            s += x; q += x * x;
        }
        s += __shfl_xor(s, 16); s += __shfl_xor(s, 32);
        q += __shfl_xor(q, 16); q += __shfl_xor(q, 32);
        if (kg == 0) {
            atomicAdd(&lsum[nt * 16 + r16], s);
            atomicAdd(&lsq [nt * 16 + r16], q);
        }
    }
    __syncthreads();                 // all waves done reading Wh/Wl
    u32* stage = (u32*)WB;           // 64 KB staging aliases Wh/Wl
    #pragma unroll
    for (int nt = 0; nt < 8; nt++) {
        #pragma unroll
        for (int j = 0; j < 4; j++) {
            int rl_ = wave * 16 + kg * 4 + j;
            int c   = nt * 16 + r16;
            stage[rl_ * 128 + c] = packsplit(v[nt][j]);
        }
    }
    __syncthreads();
    {
        uint4* g = (uint4*)(App + (size_t)blockIdx.x * 128 * 128);
        const uint4* s4 = (const uint4*)stage;
        for (int i = tid; i < 128 * 128 / 4; i += 512) g[i] = s4[i];
    }
    if (tid < 128) {
        atomicAdd(&ssum[tid], lsum[tid]);
        atomicAdd(&ssq [tid], lsq [tid]);
    }
}

// ---------------------------------------------------------------------------
// Fused level-2 pass over packed t4 (BN-B coeffs in prologue).
// Blocks [0,512): parent2-sorted gather -> p2; [512,1024): tree1 proj -> acc1.
// ---------------------------------------------------------------------------
__global__ __launch_bounds__(512) void k_l2(
    const u32* __restrict__ pp,
    const int* __restrict__ child2, const int* __restrict__ off2,
    const int* __restrict__ cnt2,
    const int* __restrict__ childT1, const int* __restrict__ offT1,
    const int* __restrict__ cntT1,
    const float* __restrict__ sumB, const float* __restrict__ sqB,
    const float* __restrict__ bng, const float* __restrict__ bnb,
    const float* __restrict__ predW,
    float* __restrict__ p2, float* __restrict__ acc1)
{
    __shared__ __align__(16) float scl[128], shl[128];
    const int tid = threadIdx.x;
    if (tid < 128) {
        float m = sumB[tid] * (1.f / N1c);
        float v = sqB[tid] * (1.f / N1c) - m * m;
        float s = bng[tid] * rsqrtf(v + EPSc);
        scl[tid] = s;
        shl[tid] = bnb[tid] - m * s;
    }
    __syncthreads();

    const int lane = tid & 31;
    const int sub  = tid >> 5;
    float4 sc4 = ((const float4*)scl)[lane];
    float4 sh4 = ((const float4*)shl)[lane];

    auto rowval = [&](int r0) {
        uint4 pv = *(const uint4*)(pp + (size_t)r0 * 128 + lane * 4);
        float4 x;
        x.x = fmaxf(fmaf(bf2f((u16)pv.x) + bf2f((u16)(pv.x >> 16)), sc4.x, sh4.x), 0.f);
        x.y = fmaxf(fmaf(bf2f((u16)pv.y) + bf2f((u16)(pv.y >> 16)), sc4.y, sh4.y), 0.f);
        x.z = fmaxf(fmaf(bf2f((u16)pv.z) + bf2f((u16)(pv.z >> 16)), sc4.z, sh4.z), 0.f);
        x.w = fmaxf(fmaf(bf2f((u16)pv.w) + bf2f((u16)(pv.w >> 16)), sc4.w, sh4.w), 0.f);
        return x;
    };

    if (blockIdx.x < 512) {
        const int t = blockIdx.x * 16 + sub;
        const int seg = t % Bc;
        const int ch  = t / Bc;
        const int beg = off2[seg], len = cnt2[seg];
        int c0 = (int)(((long long)len * ch) / 16);
        int c1 = (int)(((long long)len * (ch + 1)) / 16);
        float4 acc = make_float4(0.f, 0.f, 0.f, 0.f);
        for (int c = c0; c < c1; ++c) {
            float4 x = rowval(child2[beg + c]);
            acc.x += x.x; acc.y += x.y; acc.z += x.z; acc.w += x.w;
        }
        float* d = p2 + (size_t)seg * Hc + lane * 4;
        atomicAdd(d + 0, acc.x);
        atomicAdd(d + 1, acc.y);
        atomicAdd(d + 2, acc.z);
        atomicAdd(d + 3, acc.w);
    } else {
        float4 wreg[Cc];
        #pragma unroll
        for (int cc = 0; cc < Cc; cc++) {
            wreg[cc].x = predW[(Hc + lane*4 + 0) * Cc + cc];
            wreg[cc].y = predW[(Hc + lane*4 + 1) * Cc + cc];
            wreg[cc].z = predW[(Hc + lane*4 + 2) * Cc + cc];
            wreg[cc].w = predW[(Hc + lane*4 + 3) * Cc + cc];
        }
        const int t = (blockIdx.x - 512) * 16 + sub;
        const int tr = t & (Bc - 1);
        const int ch = t >> 9;
        const int beg = offT1[tr], len = cntT1[tr];
        int c0 = (int)(((long long)len * ch) / 16);
        int c1 = (int)(((long long)len * (ch + 1)) / 16);
        float4 acc = make_float4(0.f, 0.f, 0.f, 0.f);
        for (int c = c0; c < c1; ++c) {
            float4 x = rowval(childT1[beg + c]);
            acc.x += x.x; acc.y += x.y; acc.z += x.z; acc.w += x.w;
        }
        float pv[Cc];
        #pragma unroll
        for (int cc = 0; cc < Cc; cc++) {
            pv[cc] = acc.x * wreg[cc].x + acc.y * wreg[cc].y
                   + acc.z * wreg[cc].z + acc.w * wreg[cc].w;
        }
        #pragma unroll
        for (int o = 16; o; o >>= 1) {
            #pragma unroll
            for (int cc = 0; cc < Cc; cc++) pv[cc] += __shfl_xor(pv[cc], o, 32);
        }
        if (lane == 0) {
            #pragma unroll
            for (int cc = 0; cc < Cc; cc++) atomicAdd(&acc1[tr * Cc + cc], pv[cc]);
        }
    }
}

// ---------------------------------------------------------------------------
// fp32 GEMM for the tiny level-2 MLP (BN folded when BN_IN=1).
// ---------------------------------------------------------------------------
template<int BN_IN>
__global__ __launch_bounds__(256) void k_gemm2(
    const float* __restrict__ in, float* __restrict__ out,
    const float* __restrict__ W, const float* __restrict__ bias,
    const float* __restrict__ bn_sum, const float* __restrict__ bn_sq,
    const float* __restrict__ bn_g, const float* __restrict__ bn_b,
    float* __restrict__ ssum, float* __restrict__ ssq)
{
    __shared__ float Wlds[Hc * Hc];
    __shared__ float inl[32 * Hc];
    __shared__ __align__(16) float scl[128], shl[128];

    const int tid = threadIdx.x;
    if (BN_IN && tid < 128) {
        float m = bn_sum[tid] * (1.f / Bc);
        float v = bn_sq[tid] * (1.f / Bc) - m * m;
        float s = bn_g[tid] * rsqrtf(v + EPSc);
        scl[tid] = s;
        shl[tid] = bn_b[tid] - m * s;
    }
    {
        const float4* W4 = (const float4*)W;
        float4* Wl4 = (float4*)Wlds;
        for (int i = tid; i < Hc * Hc / 4; i += 256) Wl4[i] = W4[i];
    }
    __syncthreads();
    const int row0 = blockIdx.x * 32;
    for (int i = tid; i < 32 * 32; i += 256) {
        int r = i >> 5, g = i & 31;
        float4 v = ((const float4*)(in + (size_t)(row0 + r) * Hc))[g];
        if (BN_IN) {
            float4 sc = ((const float4*)scl)[g];
            float4 sh = ((const float4*)shl)[g];
            v.x = fmaxf(v.x * sc.x + sh.x, 0.f);
            v.y = fmaxf(v.y * sc.y + sh.y, 0.f);
            v.z = fmaxf(v.z * sc.z + sh.z, 0.f);
            v.w = fmaxf(v.w * sc.w + sh.w, 0.f);
        }
        ((float4*)(inl + r * Hc))[g] = v;
    }
    __syncthreads();

    const int rg = tid >> 5;
    const int cg = tid & 31;
    float acc[4][4] = {{0.f}};
    for (int k = 0; k < Hc; k += 4) {
        float a[4][4], w[4][4];
        #pragma unroll
        for (int r = 0; r < 4; r++) {
            float4 t = *(const float4*)&inl[(rg*4 + r) * Hc + k];
            a[r][0] = t.x; a[r][1] = t.y; a[r][2] = t.z; a[r][3] = t.w;
        }
        #pragma unroll
        for (int kk = 0; kk < 4; kk++) {
            float4 t = *(const float4*)&Wlds[(k + kk) * Hc + cg*4];
            w[kk][0] = t.x; w[kk][1] = t.y; w[kk][2] = t.z; w[kk][3] = t.w;
        }
        #pragma unroll
        for (int r = 0; r < 4; r++)
            #pragma unroll
            for (int kk = 0; kk < 4; kk++)
                #pragma unroll
                for (int c = 0; c < 4; c++)
                    acc[r][c] = fmaf(a[r][kk], w[kk][c], acc[r][c]);
    }

    float b4[4];
    #pragma unroll
    for (int c = 0; c < 4; c++) b4[c] = bias[cg*4 + c];
    float s[4] = {0.f,0.f,0.f,0.f}, q[4] = {0.f,0.f,0.f,0.f};
    #pragma unroll
    for (int r = 0; r < 4; r++) {
        float v0 = acc[r][0] + b4[0];
        float v1 = acc[r][1] + b4[1];
        float v2 = acc[r][2] + b4[2];
        float v3 = acc[r][3] + b4[3];
        float4 o; o.x = v0; o.y = v1; o.z = v2; o.w = v3;
        s[0] += v0; s[1] += v1; s[2] += v2; s[3] += v3;
        q[0] += v0*v0; q[1] += v1*v1; q[2] += v2*v2; q[3] += v3*v3;
        *(float4*)&out[(size_t)(row0 + rg*4 + r) * Hc + cg*4] = o;
    }

    __syncthreads();
    #pragma unroll
    for (int c = 0; c < 4; c++) inl[rg * Hc + cg*4 + c] = s[c];
    __syncthreads();
    if (tid < Hc) {
        float t = 0.f;
        #pragma unroll
        for (int g = 0; g < 8; g++) t += inl[g * Hc + tid];
        atomicAdd(&ssum[tid], t);
    }
    __syncthreads();
    #pragma unroll
    for (int c = 0; c < 4; c++) inl[rg * Hc + cg*4 + c] = q[c];
    __syncthreads();
    if (tid < Hc) {
        float t = 0.f;
        #pragma unroll
        for (int g = 0; g < 8; g++) t += inl[g * Hc + tid];
        atomicAdd(&ssq[tid], t);
    }
}

// ---------------------------------------------------------------------------
// Final: BN-D from stats; logits + softmax.
// ---------------------------------------------------------------------------
__global__ __launch_bounds__(128) void k_final(
    const float* __restrict__ u2,
    const float* __restrict__ sumD, const float* __restrict__ sqD,
    const float* __restrict__ bng, const float* __restrict__ bnb,
    const float* __restrict__ acc0, const float* __restrict__ acc1,
    const float* __restrict__ predW, const float* __restrict__ predb,
    float* __restrict__ out)
{
    __shared__ float h[Hc];
    __shared__ float wl[Hc * Cc];
    __shared__ float lg[Cc], ex[Cc];
    int b = blockIdx.x, t = threadIdx.x;
    for (int i = t; i < Hc * Cc; i += 128) wl[i] = predW[(2*Hc) * Cc + i];
    {
        float m = sumD[t] * (1.f / Bc);
        float v = sqD[t] * (1.f / Bc) - m * m;
        float s = bng[t] * rsqrtf(v + EPSc);
        float x = u2[(size_t)b * Hc + t];
        h[t] = fmaxf(x * s + (bnb[t] - m * s), 0.f);
    }
    __syncthreads();
    if (t < Cc) {
        float s = predb[t] + acc0[b * Cc + t] + acc1[b * Cc + t];
        for (int d = 0; d < Hc; d++) s += h[d] * wl[d * Cc + t];
        lg[t] = s;
    }
    __syncthreads();
    if (t < Cc) {
        float m = lg[0];
        #pragma unroll
        for (int c = 1; c < Cc; c++) m = fmaxf(m, lg[c]);
        ex[t] = expf(lg[t] - m);
    }
    __syncthreads();
    if (t < Cc) {
        float s = 0.f;
        #pragma unroll
        for (int c = 0; c < Cc; c++) s += ex[c];
        out[b * Cc + t] = ex[t] / s;
    }
}

extern "C" void kernel_launch(void* const* d_in, const int* in_sizes, int n_in,
                              void* d_out, int out_size, void* d_ws, size_t ws_size,
                              hipStream_t stream) {
    const float* h0      = (const float*)d_in[0];
    const int*   parent1 = (const int*)d_in[1];
    const int*   parent2 = (const int*)d_in[2];
    const int*   tree0   = (const int*)d_in[3];
    const int*   tree1   = (const int*)d_in[4];
    const float* m1W1 = (const float*)d_in[5];
    const float* m1b1 = (const float*)d_in[6];
    const float* m1bng = (const float*)d_in[7];
    const float* m1bnb = (const float*)d_in[8];
    const float* m1W2 = (const float*)d_in[9];
    const float* m1b2 = (const float*)d_in[10];
    const float* bn1g = (const float*)d_in[11];
    const float* bn1b = (const float*)d_in[12];
    const float* m2W1 = (const float*)d_in[13];
    const float* m2b1 = (const float*)d_in[14];
    const float* m2bng = (const float*)d_in[15];
    const float* m2bnb = (const float*)d_in[16];
    const float* m2W2 = (const float*)d_in[17];
    const float* m2b2 = (const float*)d_in[18];
    const float* bn2g = (const float*)d_in[19];
    const float* bn2b = (const float*)d_in[20];
    const float* predW = (const float*)d_in[21];
    const float* predb = (const float*)d_in[22];
    float* out = (float*)d_out;

    // ---- workspace layout ----
    u16* h0s = (u16*)d_ws;                              // N0*128 bf16, sorted (128 MB)
    u32* pp  = (u32*)(h0s + (size_t)N0c * Hc);          // N1*128 packed (64 MB)
    float* zbase = (float*)(pp + (size_t)N1c * Hc);
    float* p2    = zbase;                               // 512*128
    float* acc0  = p2 + Bc * Hc;                        // 5120
    float* acc1  = acc0 + Bc * Cc;                      // 5120
    float* stats = acc1 + Bc * Cc;                      // 8*128
    int* cnt1   = (int*)(stats + 8 * Hc);               // 131072
    int* cur1   = cnt1 + N1c;                           // 131072
    int* cnt2   = cur1 + N1c;                           // 512
    int* cur2   = cnt2 + Bc;
    int* cntT1  = cur2 + Bc;
    int* curT1  = cntT1 + Bc;
    // --- end of zero region ---
    int* zend   = curT1 + Bc;
    int* off1   = zend;                  // 131072
    int* bsum   = off1 + N1c;            // 512
    int* off2   = bsum + Bc;             // 512
    int* offT1  = off2 + Bc;             // 512
    int* child2 = offT1 + Bc;            // 131072
    int* childT1= child2 + N1c;          // 131072
    float* u1   = (float*)(childT1 + N1c);              // 512*128
    float* u2   = u1 + Bc * Hc;                         // 512*128

    float* sumA = stats + 0 * Hc; float* sqA = stats + 1 * Hc;
    float* sumB = stats + 2 * Hc; float* sqB = stats + 3 * Hc;
    float* sumC = stats + 4 * Hc; float* sqC = stats + 5 * Hc;
    float* sumD = stats + 6 * Hc; float* sqD = stats + 7 * Hc;

    const size_t zero_bytes = (char*)zend - (char*)zbase;
    hipMemsetAsync(zbase, 0, zero_bytes, stream);

    // ---- sorts: count, scan, (place rides on k_s) ----
    k_count_all<<<640, 256, 0, stream>>>(parent1, cnt1, parent2, cnt2, tree1, cntT1);
    k_scan_local<<<N1c / 256, 256, 0, stream>>>(cnt1, off1, bsum, N1c);
    k_scan_fin<<<514, 512, 0, stream>>>(bsum, off1, cnt2, off2, cntT1, offT1);

    // ---- level 1: stream h0 (proj + bf16 + scatter) ∥ binned places ----
    k_s<<<1088, 512, 0, stream>>>(h0, tree0, parent1, off1, cur1, predW,
                                  h0s, acc0,
                                  parent2, off2, cur2, child2,
                                  tree1, offT1, curT1, childT1);

    // ---- contiguous segment-sum -> p1 (packed split-bf16) ----
    k_gather_c<<<2048, 512, 0, stream>>>(h0s, off1, cnt1, pp);

    // ---- layer-1 MLP: two packed MFMA GEMMs in place ----
    k_gemm_mfma<0><<<N1c / 128, 512, 0, stream>>>(pp, m1W1, m1b1,
                                                  nullptr, nullptr, nullptr, nullptr,
                                                  0.f, sumA, sqA);
    k_gemm_mfma<1><<<N1c / 128, 512, 0, stream>>>(pp, m1W2, m1b2,
                                                  sumA, sqA, m1bng, m1bnb,
                                                  1.f / N1c, sumB, sqB);

    // ---- level 2: fused gather + g1 projection (packed reads) ----
    k_l2<<<1024, 512, 0, stream>>>(pp, child2, off2, cnt2,
                                   childT1, offT1, cntT1,
                                   sumB, sqB, bn1g, bn1b, predW, p2, acc1);

    // ---- layer-2 MLP (BN folded) + final ----
    k_gemm2<0><<<Bc / 32, 256, 0, stream>>>(p2, u1, m2W1, m2b1,
                                            nullptr, nullptr, nullptr, nullptr,
                                            sumC, sqC);
    k_gemm2<1><<<Bc / 32, 256, 0, stream>>>(u1, u2, m2W2, m2b2,
                                            sumC, sqC, m2bng, m2bnb,
                                            sumD, sqD);
    k_final<<<Bc, 128, 0, stream>>>(u2, sumD, sqD, bn2g, bn2b,
                                    acc0, acc1, predW, predb, out);
}